// Round 10
// baseline (1152.395 us; speedup 1.0000x reference)
//
#include <hip/hip_runtime.h>

#define INDIM 128
#define HID 256
#define NCLS 16
#define NGRAPH 64
#define CHUNK 8192

typedef __bf16 bf16_t;
typedef bf16_t bf16x8 __attribute__((ext_vector_type(8)));
typedef float f32x4 __attribute__((ext_vector_type(4)));

__device__ __forceinline__ float bfu_lo(unsigned v) {
    union { unsigned i; float f; } u; u.i = v << 16; return u.f;
}
__device__ __forceinline__ float bfu_hi(unsigned v) {
    union { unsigned i; float f; } u; u.i = v & 0xffff0000u; return u.f;
}
__device__ __forceinline__ unsigned short f2bf(float f) {  // RNE
    union { float f; unsigned i; } u; u.f = f;
    unsigned b = u.i;
    return (unsigned short)((b + 0x7fffu + ((b >> 16) & 1u)) >> 16);
}
__device__ __forceinline__ unsigned packbf(float lo, float hi) {
    return (unsigned)f2bf(lo) | ((unsigned)f2bf(hi) << 16);
}

// async 16B global->LDS
typedef __attribute__((address_space(1))) const unsigned gu32_t;
typedef __attribute__((address_space(3))) unsigned lu32_t;
__device__ __forceinline__ void gl_lds16(const void* g, void* l) {
    __builtin_amdgcn_global_load_lds((gu32_t*)g, (lu32_t*)l, 16, 0, 0);
}

// SWAR: biased uint8 bytes accumulate as packed u16 pairs (exact; deg<256 => no overflow)
#define IACC(aE, aO, v)                              \
    do {                                             \
        aE[0] += ((v).x & 0x00FF00FFu);              \
        aO[0] += (((v).x >> 8) & 0x00FF00FFu);       \
        aE[1] += ((v).y & 0x00FF00FFu);              \
        aO[1] += (((v).y >> 8) & 0x00FF00FFu);       \
        aE[2] += ((v).z & 0x00FF00FFu);              \
        aO[2] += (((v).z >> 8) & 0x00FF00FFu);       \
        aE[3] += ((v).w & 0x00FF00FFu);              \
        aO[3] += (((v).w >> 8) & 0x00FF00FFu);       \
    } while (0)

// ---------------- CSR build ----------------
__global__ void hist_kernel(const int* __restrict__ dst, int* __restrict__ deg, int E) {
    int e = blockIdx.x * blockDim.x + threadIdx.x;
    if (e < E) atomicAdd(&deg[dst[e]], 1);
}

__global__ void scan1_kernel(const int* __restrict__ deg, int* __restrict__ bsum, int n) {
    __shared__ int s[256];
    int t = threadIdx.x;
    int i = blockIdx.x * 256 + t;
    s[t] = (i < n) ? deg[i] : 0;
    __syncthreads();
    for (int off = 128; off > 0; off >>= 1) {
        if (t < off) s[t] += s[t + off];
        __syncthreads();
    }
    if (t == 0) bsum[blockIdx.x] = s[0];
}

__global__ void scan2_kernel(int* bsum, int nb) {
    __shared__ int s[1024];
    int t = threadIdx.x;
    int v = (t < nb) ? bsum[t] : 0;
    s[t] = v;
    __syncthreads();
    for (int off = 1; off < 1024; off <<= 1) {
        int u = (t >= off) ? s[t - off] : 0;
        __syncthreads();
        s[t] += u;
        __syncthreads();
    }
    if (t < nb) bsum[t] = s[t] - v;  // exclusive
}

__global__ void scan3_kernel(const int* __restrict__ deg, const int* __restrict__ bsum,
                             int* __restrict__ offs, int* __restrict__ gcur, int n) {
    __shared__ int s[256];
    int t = threadIdx.x;
    int i = blockIdx.x * 256 + t;
    int v = (i < n) ? deg[i] : 0;
    s[t] = v;
    __syncthreads();
    for (int off = 1; off < 256; off <<= 1) {
        int u = (t >= off) ? s[t - off] : 0;
        __syncthreads();
        s[t] += u;
        __syncthreads();
    }
    if (i < n) offs[i] = s[t] - v + bsum[blockIdx.x];
    if (t == 0) gcur[blockIdx.x] = bsum[blockIdx.x];
}

// ---------------- two-phase locality-aware edge sort ----------------
__global__ __launch_bounds__(256) void binA_kernel(const int* __restrict__ src,
                                                   const int* __restrict__ dst,
                                                   int* __restrict__ gcur,
                                                   unsigned* __restrict__ tmp,
                                                   int E, int nbuck) {
    __shared__ int hist[512];
    __shared__ int base[512];
    int t = threadIdx.x;
    int e0 = blockIdx.x * CHUNK;
    int e1 = min(e0 + CHUNK, E);
    for (int i = t; i < nbuck; i += 256) hist[i] = 0;
    __syncthreads();
    for (int e = e0 + t; e < e1; e += 256) atomicAdd(&hist[dst[e] >> 8], 1);
    __syncthreads();
    for (int i = t; i < nbuck; i += 256) {
        int c = hist[i];
        base[i] = (c > 0) ? atomicAdd(&gcur[i], c) : 0;
    }
    __syncthreads();
    for (int e = e0 + t; e < e1; e += 256) {
        int d = dst[e];
        int p = atomicAdd(&base[d >> 8], 1);
        tmp[p] = ((unsigned)(d & 255) << 17) | (unsigned)src[e];  // src < 2^17
    }
}

__global__ __launch_bounds__(256) void binB_kernel(const unsigned* __restrict__ tmp,
                                                   const int* __restrict__ offs,
                                                   int* __restrict__ srclist, int E, int n) {
    __shared__ int cur[256];
    int b = blockIdx.x;
    int node0 = b << 8;
    int nnodes = min(256, n - node0);
    int t = threadIdx.x;
    if (t < nnodes) cur[t] = offs[node0 + t];
    __syncthreads();
    int ebeg = offs[node0];
    int eend = (node0 + 256 < n) ? offs[node0 + 256] : E;
    for (int e = ebeg + t; e < eend; e += 256) {
        unsigned v = tmp[e];
        int p = atomicAdd(&cur[v >> 17], 1);
        srclist[p] = (int)(v & 0x1FFFFu);
    }
}

// ---------------- merged prep: cast x -> bf16 (+ global absmax of x), build Bt1/Bt2 ----------------
__global__ void prep_kernel(const float* __restrict__ x, unsigned short* __restrict__ xb,
                            const float* __restrict__ W1l, const float* __restrict__ W1r,
                            unsigned short* __restrict__ Bt1,
                            const float* __restrict__ W2l, const float* __restrict__ W2r,
                            unsigned short* __restrict__ Bt2, unsigned* __restrict__ gmaxx,
                            int castb) {
    int b = blockIdx.x, t = threadIdx.x;
    if (b < castb) {
        int i4 = (b * 256 + t) * 4;
        float4 v = *(const float4*)(x + i4);
        *(ushort4*)(xb + i4) = make_ushort4(f2bf(v.x), f2bf(v.y), f2bf(v.z), f2bf(v.w));
        float m = fmaxf(fmaxf(fabsf(v.x), fabsf(v.y)), fmaxf(fabsf(v.z), fabsf(v.w)));
#pragma unroll
        for (int off = 32; off > 0; off >>= 1) m = fmaxf(m, __shfl_xor(m, off));
        if ((t & 63) == 0) atomicMax(gmaxx, __float_as_uint(m));
    } else if (b < castb + 256) {
        int idx = (b - castb) * 256 + t;
        int nn = idx >> 8, k = idx & 255;
        float v = (k < 128) ? W1l[(size_t)k * 256 + nn] : W1r[(size_t)(k - 128) * 256 + nn];
        Bt1[(size_t)nn * 256 + k] = f2bf(v);
    } else {
        int idx = (b - castb - 256) * 256 + t;
        int nn = idx >> 9, k = idx & 511;
        float v = (k < 256) ? W2l[(size_t)k * 256 + nn] : W2r[(size_t)(k - 256) * 256 + nn];
        Bt2[(size_t)nn * 512 + k] = f2bf(v);
    }
}

// ---------------- int8 quantization (biased uint8, one global scale) ----------------
__global__ void quantx_kernel(const float* __restrict__ x, const float* __restrict__ gmaxp,
                              unsigned* __restrict__ xq, int total4) {
    int idx = blockIdx.x * blockDim.x + threadIdx.x;
    if (idx >= total4) return;
    float inv = 127.f / fmaxf(*gmaxp, 1e-20f);
    float4 v = *(const float4*)(x + idx * 4);
    int b0 = (int)fminf(fmaxf(rintf(v.x * inv), -127.f), 127.f) + 128;
    int b1 = (int)fminf(fmaxf(rintf(v.y * inv), -127.f), 127.f) + 128;
    int b2 = (int)fminf(fmaxf(rintf(v.z * inv), -127.f), 127.f) + 128;
    int b3 = (int)fminf(fmaxf(rintf(v.w * inv), -127.f), 127.f) + 128;
    xq[idx] = (unsigned)b0 | ((unsigned)b1 << 8) | ((unsigned)b2 << 16) | ((unsigned)b3 << 24);
}

__global__ void quanth_kernel(const unsigned short* __restrict__ h1, const float* __restrict__ gmaxp,
                              unsigned* __restrict__ hq, int total4) {
    int idx = blockIdx.x * blockDim.x + threadIdx.x;
    if (idx >= total4) return;
    float inv = 127.f / fmaxf(*gmaxp, 1e-20f);
    uint2 v = *(const uint2*)(h1 + idx * 4);
    // h1 >= 0 (relu); clamp guards bf16-rounding past gmax
    int b0 = (int)fminf(rintf(bfu_lo(v.x) * inv), 127.f) + 128;
    int b1 = (int)fminf(rintf(bfu_hi(v.x) * inv), 127.f) + 128;
    int b2 = (int)fminf(rintf(bfu_lo(v.y) * inv), 127.f) + 128;
    int b3 = (int)fminf(rintf(bfu_hi(v.y) * inv), 127.f) + 128;
    hq[idx] = (unsigned)b0 | ((unsigned)b1 << 8) | ((unsigned)b2 << 16) | ((unsigned)b3 << 24);
}

// ---------------- int8 mean aggregation (SWAR u16 accumulate, exact) ----------------
// agg1: 8 lanes x 16B = 128B int8 row; one load instr = 8 edges; 16-edge unroll.
__global__ void agg1_kernel(const unsigned char* __restrict__ xq, const int* __restrict__ srclist,
                            const int* __restrict__ offs, const int* __restrict__ deg,
                            const float* __restrict__ gmaxp,
                            unsigned short* __restrict__ mean, int n) {
    int gid = blockIdx.x * blockDim.x + threadIdx.x;
    int node = gid >> 6, lane = gid & 63;
    if (node >= n) return;
    int g = lane >> 3, sub = lane & 7;
    int st = __builtin_amdgcn_readfirstlane(offs[node]);
    int d = __builtin_amdgcn_readfirstlane(deg[node]);
    int end = st + d;
    unsigned aE[4] = {0, 0, 0, 0}, aO[4] = {0, 0, 0, 0};
    unsigned bE[4] = {0, 0, 0, 0}, bO[4] = {0, 0, 0, 0};
    const unsigned char* rb = xq + sub * 16;
    int e = st;
    for (; e + 15 < end; e += 16) {  // 2 loads -> 16 edges
        int s0 = srclist[e + g];
        int s1 = srclist[e + 8 + g];
        uint4 v0 = *(const uint4*)(rb + (size_t)s0 * 128);
        uint4 v1 = *(const uint4*)(rb + (size_t)s1 * 128);
        IACC(aE, aO, v0);
        IACC(bE, bO, v1);
    }
    for (; e + 7 < end; e += 8) {
        int s0 = srclist[e + g];
        uint4 v0 = *(const uint4*)(rb + (size_t)s0 * 128);
        IACC(aE, aO, v0);
    }
    int rem = end - e;
    if (rem > 0) {  // 1..7 edges; groups g >= rem contribute 0
        int s0 = srclist[e + ((g < rem) ? g : 0)];
        uint4 v0 = *(const uint4*)(rb + (size_t)s0 * 128);
        if (g < rem) IACC(aE, aO, v0);
    }
#pragma unroll
    for (int j = 0; j < 4; ++j) {
        unsigned se = aE[j] + bE[j], so = aO[j] + bO[j];
        se += (unsigned)__shfl_xor((int)se, 8);
        se += (unsigned)__shfl_xor((int)se, 16);
        se += (unsigned)__shfl_xor((int)se, 32);
        so += (unsigned)__shfl_xor((int)so, 8);
        so += (unsigned)__shfl_xor((int)so, 16);
        so += (unsigned)__shfl_xor((int)so, 32);
        aE[j] = se;
        aO[j] = so;
    }
    if (g == 0) {  // lanes 0..7
        float sc = (*gmaxp) * (1.f / 127.f);
        float invd = 1.f / fmaxf((float)d, 1.f);
        unsigned o[8];
#pragma unroll
        for (int j = 0; j < 4; ++j) {
            // cols 4j..4j+3: E=(c0,c2) O=(c1,c3)
            float m0 = sc * (float)((int)(aE[j] & 0xFFFFu) - 128 * d) * invd;
            float m1 = sc * (float)((int)(aO[j] & 0xFFFFu) - 128 * d) * invd;
            float m2 = sc * (float)((int)(aE[j] >> 16) - 128 * d) * invd;
            float m3 = sc * (float)((int)(aO[j] >> 16) - 128 * d) * invd;
            o[j * 2] = packbf(m0, m1);
            o[j * 2 + 1] = packbf(m2, m3);
        }
        uint4* p = (uint4*)(mean + (size_t)node * 128 + sub * 16);
        p[0] = make_uint4(o[0], o[1], o[2], o[3]);
        p[1] = make_uint4(o[4], o[5], o[6], o[7]);
    }
}

// agg2: 16 lanes x 16B = 256B int8 row; one load instr = 4 edges; 8-edge unroll.
__global__ void agg2_kernel(const unsigned char* __restrict__ hq, const int* __restrict__ srclist,
                            const int* __restrict__ offs, const int* __restrict__ deg,
                            const float* __restrict__ gmaxp,
                            unsigned short* __restrict__ mean, int n) {
    int gid = blockIdx.x * blockDim.x + threadIdx.x;
    int node = gid >> 6, lane = gid & 63;
    if (node >= n) return;
    int g = lane >> 4, sub = lane & 15;
    int st = __builtin_amdgcn_readfirstlane(offs[node]);
    int d = __builtin_amdgcn_readfirstlane(deg[node]);
    int end = st + d;
    unsigned aE[4] = {0, 0, 0, 0}, aO[4] = {0, 0, 0, 0};
    unsigned bE[4] = {0, 0, 0, 0}, bO[4] = {0, 0, 0, 0};
    const unsigned char* rb = hq + sub * 16;
    int e = st;
    for (; e + 7 < end; e += 8) {  // 2 loads -> 8 edges
        int s0 = srclist[e + g];
        int s1 = srclist[e + 4 + g];
        uint4 v0 = *(const uint4*)(rb + (size_t)s0 * 256);
        uint4 v1 = *(const uint4*)(rb + (size_t)s1 * 256);
        IACC(aE, aO, v0);
        IACC(bE, bO, v1);
    }
    for (; e + 3 < end; e += 4) {
        int s0 = srclist[e + g];
        uint4 v0 = *(const uint4*)(rb + (size_t)s0 * 256);
        IACC(aE, aO, v0);
    }
    int rem = end - e;
    if (rem > 0) {  // 1..3 edges
        int s0 = srclist[e + ((g < rem) ? g : 0)];
        uint4 v0 = *(const uint4*)(rb + (size_t)s0 * 256);
        if (g < rem) IACC(aE, aO, v0);
    }
#pragma unroll
    for (int j = 0; j < 4; ++j) {
        unsigned se = aE[j] + bE[j], so = aO[j] + bO[j];
        se += (unsigned)__shfl_xor((int)se, 16);
        se += (unsigned)__shfl_xor((int)se, 32);
        so += (unsigned)__shfl_xor((int)so, 16);
        so += (unsigned)__shfl_xor((int)so, 32);
        aE[j] = se;
        aO[j] = so;
    }
    if (g == 0) {  // lanes 0..15
        float sc = (*gmaxp) * (1.f / 127.f);
        float invd = 1.f / fmaxf((float)d, 1.f);
        unsigned o[8];
#pragma unroll
        for (int j = 0; j < 4; ++j) {
            float m0 = sc * (float)((int)(aE[j] & 0xFFFFu) - 128 * d) * invd;
            float m1 = sc * (float)((int)(aO[j] & 0xFFFFu) - 128 * d) * invd;
            float m2 = sc * (float)((int)(aE[j] >> 16) - 128 * d) * invd;
            float m3 = sc * (float)((int)(aO[j] >> 16) - 128 * d) * invd;
            o[j * 2] = packbf(m0, m1);
            o[j * 2 + 1] = packbf(m2, m3);
        }
        uint4* p = (uint4*)(mean + (size_t)node * 256 + sub * 16);
        p[0] = make_uint4(o[0], o[1], o[2], o[3]);
        p[1] = make_uint4(o[4], o[5], o[6], o[7]);
    }
}

// ======== MFMA GEMM with async A-staging (R6-proven); optional global-max epilogue ========
template <int KH>  // per-half K: 128 (layer1) or 256 (layer2)
__global__ __launch_bounds__(256) void gemm_kernel(
        const bf16_t* __restrict__ A1, const bf16_t* __restrict__ A2,
        const bf16_t* __restrict__ Bt, const float* __restrict__ bias,
        unsigned short* __restrict__ H, unsigned* __restrict__ gmaxout, int M) {
    constexpr int KT = 2 * KH;
    constexpr int NC = KT / 64;
    constexpr int CPH = KH / 64;
    __shared__ unsigned short As[64 * 64];  // 8 KB
    int t = threadIdx.x, wave = t >> 6, lane = t & 63;
    int quad = lane >> 4, l16 = lane & 15;
    int row0 = blockIdx.x * 64, n0 = wave * 64;

    f32x4 acc[4][4];
#pragma unroll
    for (int i = 0; i < 4; ++i)
#pragma unroll
        for (int j = 0; j < 4; ++j) acc[i][j] = (f32x4)(0.f);

    int rA = wave * 8 + (lane >> 3);
    int kb = lane & 7;
    int kswA = (kb ^ (rA & 7)) << 3;
    unsigned short* ldsA = &As[(size_t)(wave * 8) * 64];
    unsigned short* ldsB = &As[(size_t)(32 + wave * 8) * 64];

    const bf16_t* Bp = Bt + (size_t)(n0 + l16) * KT + quad * 8;

    for (int c = 0; c < NC; ++c) {
        const bf16_t* Ah = (c < CPH) ? A1 : A2;
        int kk = ((c < CPH) ? c : (c - CPH)) * 64;
        gl_lds16(Ah + (size_t)(row0 + rA) * KH + kk + kswA, ldsA);
        gl_lds16(Ah + (size_t)(row0 + 32 + rA) * KH + kk + kswA, ldsB);
        __syncthreads();
        int bk = c * 64;
#pragma unroll
        for (int sub = 0; sub < 2; ++sub) {
            bf16x8 af[4], bfr[4];
#pragma unroll
            for (int mi = 0; mi < 4; ++mi) {
                int r = mi * 16 + l16;
                int qb = sub * 4 + quad;
                af[mi] = *(const bf16x8*)&As[r * 64 + ((qb ^ (r & 7)) << 3)];
            }
#pragma unroll
            for (int ni = 0; ni < 4; ++ni)
                bfr[ni] = *(const bf16x8*)(Bp + (size_t)(ni * 16) * KT + bk + sub * 32);
#pragma unroll
            for (int mi = 0; mi < 4; ++mi)
#pragma unroll
                for (int ni = 0; ni < 4; ++ni)
                    acc[mi][ni] = __builtin_amdgcn_mfma_f32_16x16x32_bf16(
                        af[mi], bfr[ni], acc[mi][ni], 0, 0, 0);
        }
        __syncthreads();
    }

    float bv[4];
#pragma unroll
    for (int ni = 0; ni < 4; ++ni) bv[ni] = bias[n0 + ni * 16 + l16];
    float mloc = 0.f;
#pragma unroll
    for (int mi = 0; mi < 4; ++mi) {
#pragma unroll
        for (int r = 0; r < 4; ++r) {
            int row = row0 + mi * 16 + quad * 4 + r;
            if (row < M) {
#pragma unroll
                for (int ni = 0; ni < 4; ++ni) {
                    int col = n0 + ni * 16 + l16;
                    float hv = fmaxf(acc[mi][ni][r] + bv[ni], 0.f);
                    mloc = fmaxf(mloc, hv);  // valid rows only
                    H[(size_t)row * 256 + col] = f2bf(hv);
                }
            }
        }
    }
    if (gmaxout) {
#pragma unroll
        for (int off = 32; off > 0; off >>= 1) mloc = fmaxf(mloc, __shfl_xor(mloc, off));
        if (lane == 0) atomicMax(gmaxout, __float_as_uint(mloc));
    }
}

// ---------------- segmented mean pool (R9-proven: 64 rows/block, 4-row unroll) ----------------
__global__ __launch_bounds__(256) void pool_kernel(const unsigned short* __restrict__ h2,
                                                   const int* __restrict__ batch,
                                                   float* __restrict__ g, float* __restrict__ cnt,
                                                   int n) {
    int col = threadIdx.x;
    int row0 = blockIdx.x * 64;
    int rend = min(row0 + 64, n);
    float acc = 0.f;
    int cur = -1, seglen = 0;
    int r = row0;
    for (; r + 3 < rend; r += 4) {
        int b0 = batch[r], b1 = batch[r + 1], b2 = batch[r + 2], b3 = batch[r + 3];
        unsigned short v0 = h2[(size_t)r * 256 + col];
        unsigned short v1 = h2[(size_t)(r + 1) * 256 + col];
        unsigned short v2 = h2[(size_t)(r + 2) * 256 + col];
        unsigned short v3 = h2[(size_t)(r + 3) * 256 + col];
        int bs[4] = {b0, b1, b2, b3};
        unsigned short vs[4] = {v0, v1, v2, v3};
#pragma unroll
        for (int j = 0; j < 4; ++j) {
            if (bs[j] != cur) {
                if (cur >= 0) {
                    atomicAdd(&g[cur * 256 + col], acc);
                    if (col == 0) atomicAdd(&cnt[cur], (float)seglen);
                }
                acc = 0.f; cur = bs[j]; seglen = 0;
            }
            union { unsigned i; float f; } u;
            u.i = ((unsigned)vs[j]) << 16;
            acc += u.f;
            seglen++;
        }
    }
    for (; r < rend; ++r) {
        int b = batch[r];
        if (b != cur) {
            if (cur >= 0) {
                atomicAdd(&g[cur * 256 + col], acc);
                if (col == 0) atomicAdd(&cnt[cur], (float)seglen);
            }
            acc = 0.f; cur = b; seglen = 0;
        }
        union { unsigned i; float f; } u;
        u.i = ((unsigned)h2[(size_t)r * 256 + col]) << 16;
        acc += u.f;
        seglen++;
    }
    if (cur >= 0) {
        atomicAdd(&g[cur * 256 + col], acc);
        if (col == 0) atomicAdd(&cnt[cur], (float)seglen);
    }
}

// ---------------- classifier ----------------
__global__ void final_kernel(const float* __restrict__ g, const float* __restrict__ cnt,
                             const float* __restrict__ fcW, const float* __restrict__ fcb,
                             float* __restrict__ out) {
    int t = threadIdx.x;
    for (int o = t; o < NGRAPH * NCLS; o += 256) {
        int gi = o >> 4, c = o & 15;
        float inv = 1.f / fmaxf(cnt[gi], 1.f);
        float dot = 0.f;
        for (int k = 0; k < 256; ++k) dot += g[gi * 256 + k] * fcW[k * 16 + c];
        out[o] = dot * inv + fcb[c];
    }
}

extern "C" void kernel_launch(void* const* d_in, const int* in_sizes, int n_in, void* d_out,
                              int out_size, void* d_ws, size_t ws_size, hipStream_t stream) {
    const float* x   = (const float*)d_in[0];
    const int* edge  = (const int*)d_in[1];
    const int* batch = (const int*)d_in[2];
    const float* W1l = (const float*)d_in[3];
    const float* b1  = (const float*)d_in[4];
    const float* W1r = (const float*)d_in[5];
    const float* W2l = (const float*)d_in[6];
    const float* b2  = (const float*)d_in[7];
    const float* W2r = (const float*)d_in[8];
    const float* fcW = (const float*)d_in[9];
    const float* fcb = (const float*)d_in[10];
    float* out = (float*)d_out;

    const int n = in_sizes[0] / INDIM;   // 100000
    const int E = in_sizes[1] / 2;       // 1600000
    const int* src = edge;
    const int* dst = edge + E;
    const int nbuck = (n + 255) >> 8;    // 391

    char* ws = (char*)d_ws;
    size_t off = 0;
    auto alloc = [&](size_t bytes) {
        size_t p = off;
        off = (off + bytes + 511) & ~(size_t)511;
        return p;
    };
    size_t offs_o    = alloc((size_t)n * 4);
    size_t deg_o     = alloc((size_t)n * 4);          // zeroed
    size_t cnt_o     = alloc(64 * 4);                 // zeroed
    size_t g_o       = alloc(64 * 256 * 4);           // zeroed
    size_t gmax_o    = alloc(8);                      // zeroed: gmaxx, gmaxh
    size_t zero_end  = off;
    size_t bsum_o    = alloc(1024 * 4);
    size_t gcur_o    = alloc(512 * 4);
    size_t srclist_o = alloc((size_t)E * 4);
    size_t bt1_o     = alloc(256 * 256 * 2);
    size_t bt2_o     = alloc(256 * 512 * 2);
    size_t xbm2_o    = alloc((size_t)n * 256 * 2);    // xb16 (lower half) + xq8 (upper half) -> mean2
    size_t mean1_o   = alloc((size_t)n * 128 * 2);
    size_t h1_o      = alloc((size_t)n * 256 * 2);
    size_t h2_o      = alloc((size_t)n * 256 * 2);    // tmp (first 6.4MB) / hq8 (upper half) -> h2b

    int*   offs    = (int*)(ws + offs_o);
    int*   deg     = (int*)(ws + deg_o);
    float* cnt     = (float*)(ws + cnt_o);
    float* g       = (float*)(ws + g_o);
    unsigned* gmaxx = (unsigned*)(ws + gmax_o);
    unsigned* gmaxh = (unsigned*)(ws + gmax_o + 4);
    int*   bsum    = (int*)(ws + bsum_o);
    int*   gcur    = (int*)(ws + gcur_o);
    int*   srclist = (int*)(ws + srclist_o);
    unsigned short* Bt1   = (unsigned short*)(ws + bt1_o);
    unsigned short* Bt2   = (unsigned short*)(ws + bt2_o);
    unsigned short* xb16  = (unsigned short*)(ws + xbm2_o);                      // dead after gemm1
    unsigned char*  xq8   = (unsigned char*)(ws + xbm2_o + (size_t)n * 256);     // dead after agg1
    unsigned short* mean2 = (unsigned short*)(ws + xbm2_o);                      // written by agg2
    unsigned short* mean1 = (unsigned short*)(ws + mean1_o);
    unsigned short* h1b   = (unsigned short*)(ws + h1_o);
    unsigned*       tmp   = (unsigned*)(ws + h2_o);                              // dead after binB
    unsigned char*  hq8   = (unsigned char*)(ws + h2_o + (size_t)n * 256);       // dead after agg2
    unsigned short* h2b   = (unsigned short*)(ws + h2_o);                        // written by gemm2

    hipMemsetAsync(ws + deg_o, 0, zero_end - deg_o, stream);

    int eb = (E + 255) / 256;
    int nb = (n + 255) / 256;  // 391
    hist_kernel<<<eb, 256, 0, stream>>>(dst, deg, E);
    scan1_kernel<<<nb, 256, 0, stream>>>(deg, bsum, n);
    scan2_kernel<<<1, 1024, 0, stream>>>(bsum, nb);
    scan3_kernel<<<nb, 256, 0, stream>>>(deg, bsum, offs, gcur, n);
    binA_kernel<<<(E + CHUNK - 1) / CHUNK, 256, 0, stream>>>(src, dst, gcur, tmp, E, nbuck);
    binB_kernel<<<nbuck, 256, 0, stream>>>(tmp, offs, srclist, E, n);

    int castb = n * INDIM / 4 / 256;  // 12500
    prep_kernel<<<castb + 256 + 512, 256, 0, stream>>>(x, xb16, W1l, W1r, Bt1, W2l, W2r, Bt2,
                                                       gmaxx, castb);
    int xq4 = n * INDIM / 4;   // 3.2M
    quantx_kernel<<<(xq4 + 255) / 256, 256, 0, stream>>>(x, (const float*)gmaxx, (unsigned*)xq8, xq4);

    int aggb = (n * 64 + 255) / 256;
    int gemmb = (n + 63) / 64;  // 1563

    agg1_kernel<<<aggb, 256, 0, stream>>>(xq8, srclist, offs, deg, (const float*)gmaxx, mean1, n);
    gemm_kernel<128><<<gemmb, 256, 0, stream>>>(
        (const bf16_t*)mean1, (const bf16_t*)xb16, (const bf16_t*)Bt1, b1, h1b, gmaxh, n);
    int hq4 = n * HID / 4;     // 6.4M
    quanth_kernel<<<(hq4 + 255) / 256, 256, 0, stream>>>(h1b, (const float*)gmaxh, (unsigned*)hq8, hq4);
    agg2_kernel<<<aggb, 256, 0, stream>>>(hq8, srclist, offs, deg, (const float*)gmaxh, mean2, n);
    gemm_kernel<256><<<gemmb, 256, 0, stream>>>(
        (const bf16_t*)mean2, (const bf16_t*)h1b, (const bf16_t*)Bt2, b2, h2b,
        (unsigned*)nullptr, n);

    pool_kernel<<<(n + 63) / 64, 256, 0, stream>>>(h2b, batch, g, cnt, n);
    final_kernel<<<1, 256, 0, stream>>>(g, cnt, fcW, fcb, out);
}

// Round 11
// 554.749 us; speedup vs baseline: 2.0773x; 2.0773x over previous
//
#include <hip/hip_runtime.h>

#define INDIM 128
#define HID 256
#define NCLS 16
#define NGRAPH 64
#define CHUNK 8192

typedef __bf16 bf16_t;
typedef bf16_t bf16x8 __attribute__((ext_vector_type(8)));
typedef float f32x4 __attribute__((ext_vector_type(4)));

__device__ __forceinline__ float bfu_lo(unsigned v) {
    union { unsigned i; float f; } u; u.i = v << 16; return u.f;
}
__device__ __forceinline__ float bfu_hi(unsigned v) {
    union { unsigned i; float f; } u; u.i = v & 0xffff0000u; return u.f;
}
__device__ __forceinline__ unsigned short f2bf(float f) {  // RNE
    union { float f; unsigned i; } u; u.f = f;
    unsigned b = u.i;
    return (unsigned short)((b + 0x7fffu + ((b >> 16) & 1u)) >> 16);
}
__device__ __forceinline__ unsigned packbf(float lo, float hi) {
    return (unsigned)f2bf(lo) | ((unsigned)f2bf(hi) << 16);
}

// async 16B global->LDS
typedef __attribute__((address_space(1))) const unsigned gu32_t;
typedef __attribute__((address_space(3))) unsigned lu32_t;
__device__ __forceinline__ void gl_lds16(const void* g, void* l) {
    __builtin_amdgcn_global_load_lds((gu32_t*)g, (lu32_t*)l, 16, 0, 0);
}

// SWAR: biased uint8 bytes accumulate as packed u16 pairs (exact; deg<256 => no overflow)
#define IACC(aE, aO, v)                              \
    do {                                             \
        aE[0] += ((v).x & 0x00FF00FFu);              \
        aO[0] += (((v).x >> 8) & 0x00FF00FFu);       \
        aE[1] += ((v).y & 0x00FF00FFu);              \
        aO[1] += (((v).y >> 8) & 0x00FF00FFu);       \
        aE[2] += ((v).z & 0x00FF00FFu);              \
        aO[2] += (((v).z >> 8) & 0x00FF00FFu);       \
        aE[3] += ((v).w & 0x00FF00FFu);              \
        aO[3] += (((v).w >> 8) & 0x00FF00FFu);       \
    } while (0)

// ---------------- CSR build ----------------
__global__ void hist_kernel(const int* __restrict__ dst, int* __restrict__ deg, int E) {
    int e = blockIdx.x * blockDim.x + threadIdx.x;
    if (e < E) atomicAdd(&deg[dst[e]], 1);
}

__global__ void scan1_kernel(const int* __restrict__ deg, int* __restrict__ bsum, int n) {
    __shared__ int s[256];
    int t = threadIdx.x;
    int i = blockIdx.x * 256 + t;
    s[t] = (i < n) ? deg[i] : 0;
    __syncthreads();
    for (int off = 128; off > 0; off >>= 1) {
        if (t < off) s[t] += s[t + off];
        __syncthreads();
    }
    if (t == 0) bsum[blockIdx.x] = s[0];
}

__global__ void scan2_kernel(int* bsum, int nb) {
    __shared__ int s[1024];
    int t = threadIdx.x;
    int v = (t < nb) ? bsum[t] : 0;
    s[t] = v;
    __syncthreads();
    for (int off = 1; off < 1024; off <<= 1) {
        int u = (t >= off) ? s[t - off] : 0;
        __syncthreads();
        s[t] += u;
        __syncthreads();
    }
    if (t < nb) bsum[t] = s[t] - v;  // exclusive
}

__global__ void scan3_kernel(const int* __restrict__ deg, const int* __restrict__ bsum,
                             int* __restrict__ offs, int* __restrict__ gcur, int n) {
    __shared__ int s[256];
    int t = threadIdx.x;
    int i = blockIdx.x * 256 + t;
    int v = (i < n) ? deg[i] : 0;
    s[t] = v;
    __syncthreads();
    for (int off = 1; off < 256; off <<= 1) {
        int u = (t >= off) ? s[t - off] : 0;
        __syncthreads();
        s[t] += u;
        __syncthreads();
    }
    if (i < n) offs[i] = s[t] - v + bsum[blockIdx.x];
    if (t == 0) gcur[blockIdx.x] = bsum[blockIdx.x];
}

// ---------------- two-phase locality-aware edge sort ----------------
__global__ __launch_bounds__(256) void binA_kernel(const int* __restrict__ src,
                                                   const int* __restrict__ dst,
                                                   int* __restrict__ gcur,
                                                   unsigned* __restrict__ tmp,
                                                   int E, int nbuck) {
    __shared__ int hist[512];
    __shared__ int base[512];
    int t = threadIdx.x;
    int e0 = blockIdx.x * CHUNK;
    int e1 = min(e0 + CHUNK, E);
    for (int i = t; i < nbuck; i += 256) hist[i] = 0;
    __syncthreads();
    for (int e = e0 + t; e < e1; e += 256) atomicAdd(&hist[dst[e] >> 8], 1);
    __syncthreads();
    for (int i = t; i < nbuck; i += 256) {
        int c = hist[i];
        base[i] = (c > 0) ? atomicAdd(&gcur[i], c) : 0;
    }
    __syncthreads();
    for (int e = e0 + t; e < e1; e += 256) {
        int d = dst[e];
        int p = atomicAdd(&base[d >> 8], 1);
        tmp[p] = ((unsigned)(d & 255) << 17) | (unsigned)src[e];  // src < 2^17
    }
}

__global__ __launch_bounds__(256) void binB_kernel(const unsigned* __restrict__ tmp,
                                                   const int* __restrict__ offs,
                                                   int* __restrict__ srclist, int E, int n) {
    __shared__ int cur[256];
    int b = blockIdx.x;
    int node0 = b << 8;
    int nnodes = min(256, n - node0);
    int t = threadIdx.x;
    if (t < nnodes) cur[t] = offs[node0 + t];
    __syncthreads();
    int ebeg = offs[node0];
    int eend = (node0 + 256 < n) ? offs[node0 + 256] : E;
    for (int e = ebeg + t; e < eend; e += 256) {
        unsigned v = tmp[e];
        int p = atomicAdd(&cur[v >> 17], 1);
        srclist[p] = (int)(v & 0x1FFFFu);
    }
}

// ---------------- merged prep: cast x -> bf16 + PER-BLOCK max (plain store), build Bt1/Bt2 ----
// R10 post-mortem: 50K same-address atomicMax = 573 us (~11.5 ns each, serialized across
// XCDs). Per-block partials via plain stores + tiny reduce kernel instead.
__global__ void prep_kernel(const float* __restrict__ x, unsigned short* __restrict__ xb,
                            const float* __restrict__ W1l, const float* __restrict__ W1r,
                            unsigned short* __restrict__ Bt1,
                            const float* __restrict__ W2l, const float* __restrict__ W2r,
                            unsigned short* __restrict__ Bt2, float* __restrict__ pmaxx,
                            int castb) {
    __shared__ float wmax[4];
    int b = blockIdx.x, t = threadIdx.x;
    if (b < castb) {
        int i4 = (b * 256 + t) * 4;
        float4 v = *(const float4*)(x + i4);
        *(ushort4*)(xb + i4) = make_ushort4(f2bf(v.x), f2bf(v.y), f2bf(v.z), f2bf(v.w));
        float m = fmaxf(fmaxf(fabsf(v.x), fabsf(v.y)), fmaxf(fabsf(v.z), fabsf(v.w)));
#pragma unroll
        for (int off = 32; off > 0; off >>= 1) m = fmaxf(m, __shfl_xor(m, off));
        if ((t & 63) == 0) wmax[t >> 6] = m;
        __syncthreads();
        if (t == 0)
            pmaxx[b] = fmaxf(fmaxf(wmax[0], wmax[1]), fmaxf(wmax[2], wmax[3]));
    } else if (b < castb + 256) {
        int idx = (b - castb) * 256 + t;
        int nn = idx >> 8, k = idx & 255;
        float v = (k < 128) ? W1l[(size_t)k * 256 + nn] : W1r[(size_t)(k - 128) * 256 + nn];
        Bt1[(size_t)nn * 256 + k] = f2bf(v);
    } else {
        int idx = (b - castb - 256) * 256 + t;
        int nn = idx >> 9, k = idx & 511;
        float v = (k < 256) ? W2l[(size_t)k * 256 + nn] : W2r[(size_t)(k - 256) * 256 + nn];
        Bt2[(size_t)nn * 512 + k] = f2bf(v);
    }
}

// single-block fold of per-block partial maxima
__global__ void reducemax_kernel(const float* __restrict__ pmax, int cnt,
                                 float* __restrict__ gmax) {
    __shared__ float wmax[4];
    int t = threadIdx.x;
    float m = 0.f;
    for (int i = t; i < cnt; i += 256) m = fmaxf(m, pmax[i]);
#pragma unroll
    for (int off = 32; off > 0; off >>= 1) m = fmaxf(m, __shfl_xor(m, off));
    if ((t & 63) == 0) wmax[t >> 6] = m;
    __syncthreads();
    if (t == 0) gmax[0] = fmaxf(fmaxf(wmax[0], wmax[1]), fmaxf(wmax[2], wmax[3]));
}

// ---------------- int8 quantization (biased uint8, one global scale) ----------------
__global__ void quantx_kernel(const float* __restrict__ x, const float* __restrict__ gmaxp,
                              unsigned* __restrict__ xq, int total4) {
    int idx = blockIdx.x * blockDim.x + threadIdx.x;
    if (idx >= total4) return;
    float inv = 127.f / fmaxf(*gmaxp, 1e-20f);
    float4 v = *(const float4*)(x + idx * 4);
    int b0 = (int)fminf(fmaxf(rintf(v.x * inv), -127.f), 127.f) + 128;
    int b1 = (int)fminf(fmaxf(rintf(v.y * inv), -127.f), 127.f) + 128;
    int b2 = (int)fminf(fmaxf(rintf(v.z * inv), -127.f), 127.f) + 128;
    int b3 = (int)fminf(fmaxf(rintf(v.w * inv), -127.f), 127.f) + 128;
    xq[idx] = (unsigned)b0 | ((unsigned)b1 << 8) | ((unsigned)b2 << 16) | ((unsigned)b3 << 24);
}

__global__ void quanth_kernel(const unsigned short* __restrict__ h1, const float* __restrict__ gmaxp,
                              unsigned* __restrict__ hq, int total4) {
    int idx = blockIdx.x * blockDim.x + threadIdx.x;
    if (idx >= total4) return;
    float inv = 127.f / fmaxf(*gmaxp, 1e-20f);
    uint2 v = *(const uint2*)(h1 + idx * 4);
    // h1 >= 0 (relu); clamp guards bf16-rounding past gmax
    int b0 = (int)fminf(rintf(bfu_lo(v.x) * inv), 127.f) + 128;
    int b1 = (int)fminf(rintf(bfu_hi(v.x) * inv), 127.f) + 128;
    int b2 = (int)fminf(rintf(bfu_lo(v.y) * inv), 127.f) + 128;
    int b3 = (int)fminf(rintf(bfu_hi(v.y) * inv), 127.f) + 128;
    hq[idx] = (unsigned)b0 | ((unsigned)b1 << 8) | ((unsigned)b2 << 16) | ((unsigned)b3 << 24);
}

// ---------------- int8 mean aggregation (SWAR u16 accumulate, exact) ----------------
// agg1: 8 lanes x 16B = 128B int8 row; one load instr = 8 edges; 16-edge unroll.
__global__ void agg1_kernel(const unsigned char* __restrict__ xq, const int* __restrict__ srclist,
                            const int* __restrict__ offs, const int* __restrict__ deg,
                            const float* __restrict__ gmaxp,
                            unsigned short* __restrict__ mean, int n) {
    int gid = blockIdx.x * blockDim.x + threadIdx.x;
    int node = gid >> 6, lane = gid & 63;
    if (node >= n) return;
    int g = lane >> 3, sub = lane & 7;
    int st = __builtin_amdgcn_readfirstlane(offs[node]);
    int d = __builtin_amdgcn_readfirstlane(deg[node]);
    int end = st + d;
    unsigned aE[4] = {0, 0, 0, 0}, aO[4] = {0, 0, 0, 0};
    unsigned bE[4] = {0, 0, 0, 0}, bO[4] = {0, 0, 0, 0};
    const unsigned char* rb = xq + sub * 16;
    int e = st;
    for (; e + 15 < end; e += 16) {  // 2 loads -> 16 edges
        int s0 = srclist[e + g];
        int s1 = srclist[e + 8 + g];
        uint4 v0 = *(const uint4*)(rb + (size_t)s0 * 128);
        uint4 v1 = *(const uint4*)(rb + (size_t)s1 * 128);
        IACC(aE, aO, v0);
        IACC(bE, bO, v1);
    }
    for (; e + 7 < end; e += 8) {
        int s0 = srclist[e + g];
        uint4 v0 = *(const uint4*)(rb + (size_t)s0 * 128);
        IACC(aE, aO, v0);
    }
    int rem = end - e;
    if (rem > 0) {  // 1..7 edges; groups g >= rem contribute 0
        int s0 = srclist[e + ((g < rem) ? g : 0)];
        uint4 v0 = *(const uint4*)(rb + (size_t)s0 * 128);
        if (g < rem) IACC(aE, aO, v0);
    }
#pragma unroll
    for (int j = 0; j < 4; ++j) {
        unsigned se = aE[j] + bE[j], so = aO[j] + bO[j];
        se += (unsigned)__shfl_xor((int)se, 8);
        se += (unsigned)__shfl_xor((int)se, 16);
        se += (unsigned)__shfl_xor((int)se, 32);
        so += (unsigned)__shfl_xor((int)so, 8);
        so += (unsigned)__shfl_xor((int)so, 16);
        so += (unsigned)__shfl_xor((int)so, 32);
        aE[j] = se;
        aO[j] = so;
    }
    if (g == 0) {  // lanes 0..7
        float sc = (*gmaxp) * (1.f / 127.f);
        float invd = 1.f / fmaxf((float)d, 1.f);
        unsigned o[8];
#pragma unroll
        for (int j = 0; j < 4; ++j) {
            float m0 = sc * (float)((int)(aE[j] & 0xFFFFu) - 128 * d) * invd;
            float m1 = sc * (float)((int)(aO[j] & 0xFFFFu) - 128 * d) * invd;
            float m2 = sc * (float)((int)(aE[j] >> 16) - 128 * d) * invd;
            float m3 = sc * (float)((int)(aO[j] >> 16) - 128 * d) * invd;
            o[j * 2] = packbf(m0, m1);
            o[j * 2 + 1] = packbf(m2, m3);
        }
        uint4* p = (uint4*)(mean + (size_t)node * 128 + sub * 16);
        p[0] = make_uint4(o[0], o[1], o[2], o[3]);
        p[1] = make_uint4(o[4], o[5], o[6], o[7]);
    }
}

// agg2: 16 lanes x 16B = 256B int8 row; one load instr = 4 edges; 8-edge unroll.
__global__ void agg2_kernel(const unsigned char* __restrict__ hq, const int* __restrict__ srclist,
                            const int* __restrict__ offs, const int* __restrict__ deg,
                            const float* __restrict__ gmaxp,
                            unsigned short* __restrict__ mean, int n) {
    int gid = blockIdx.x * blockDim.x + threadIdx.x;
    int node = gid >> 6, lane = gid & 63;
    if (node >= n) return;
    int g = lane >> 4, sub = lane & 15;
    int st = __builtin_amdgcn_readfirstlane(offs[node]);
    int d = __builtin_amdgcn_readfirstlane(deg[node]);
    int end = st + d;
    unsigned aE[4] = {0, 0, 0, 0}, aO[4] = {0, 0, 0, 0};
    unsigned bE[4] = {0, 0, 0, 0}, bO[4] = {0, 0, 0, 0};
    const unsigned char* rb = hq + sub * 16;
    int e = st;
    for (; e + 7 < end; e += 8) {  // 2 loads -> 8 edges
        int s0 = srclist[e + g];
        int s1 = srclist[e + 4 + g];
        uint4 v0 = *(const uint4*)(rb + (size_t)s0 * 256);
        uint4 v1 = *(const uint4*)(rb + (size_t)s1 * 256);
        IACC(aE, aO, v0);
        IACC(bE, bO, v1);
    }
    for (; e + 3 < end; e += 4) {
        int s0 = srclist[e + g];
        uint4 v0 = *(const uint4*)(rb + (size_t)s0 * 256);
        IACC(aE, aO, v0);
    }
    int rem = end - e;
    if (rem > 0) {  // 1..3 edges
        int s0 = srclist[e + ((g < rem) ? g : 0)];
        uint4 v0 = *(const uint4*)(rb + (size_t)s0 * 256);
        if (g < rem) IACC(aE, aO, v0);
    }
#pragma unroll
    for (int j = 0; j < 4; ++j) {
        unsigned se = aE[j] + bE[j], so = aO[j] + bO[j];
        se += (unsigned)__shfl_xor((int)se, 16);
        se += (unsigned)__shfl_xor((int)se, 32);
        so += (unsigned)__shfl_xor((int)so, 16);
        so += (unsigned)__shfl_xor((int)so, 32);
        aE[j] = se;
        aO[j] = so;
    }
    if (g == 0) {  // lanes 0..15
        float sc = (*gmaxp) * (1.f / 127.f);
        float invd = 1.f / fmaxf((float)d, 1.f);
        unsigned o[8];
#pragma unroll
        for (int j = 0; j < 4; ++j) {
            float m0 = sc * (float)((int)(aE[j] & 0xFFFFu) - 128 * d) * invd;
            float m1 = sc * (float)((int)(aO[j] & 0xFFFFu) - 128 * d) * invd;
            float m2 = sc * (float)((int)(aE[j] >> 16) - 128 * d) * invd;
            float m3 = sc * (float)((int)(aO[j] >> 16) - 128 * d) * invd;
            o[j * 2] = packbf(m0, m1);
            o[j * 2 + 1] = packbf(m2, m3);
        }
        uint4* p = (uint4*)(mean + (size_t)node * 256 + sub * 16);
        p[0] = make_uint4(o[0], o[1], o[2], o[3]);
        p[1] = make_uint4(o[4], o[5], o[6], o[7]);
    }
}

// ======== MFMA GEMM with async A-staging; optional per-block max (plain store) ========
template <int KH>  // per-half K: 128 (layer1) or 256 (layer2)
__global__ __launch_bounds__(256) void gemm_kernel(
        const bf16_t* __restrict__ A1, const bf16_t* __restrict__ A2,
        const bf16_t* __restrict__ Bt, const float* __restrict__ bias,
        unsigned short* __restrict__ H, float* __restrict__ pmax, int M) {
    constexpr int KT = 2 * KH;
    constexpr int NC = KT / 64;
    constexpr int CPH = KH / 64;
    __shared__ unsigned short As[64 * 64];  // 8 KB
    __shared__ float wmax[4];
    int t = threadIdx.x, wave = t >> 6, lane = t & 63;
    int quad = lane >> 4, l16 = lane & 15;
    int row0 = blockIdx.x * 64, n0 = wave * 64;

    f32x4 acc[4][4];
#pragma unroll
    for (int i = 0; i < 4; ++i)
#pragma unroll
        for (int j = 0; j < 4; ++j) acc[i][j] = (f32x4)(0.f);

    int rA = wave * 8 + (lane >> 3);
    int kb = lane & 7;
    int kswA = (kb ^ (rA & 7)) << 3;
    unsigned short* ldsA = &As[(size_t)(wave * 8) * 64];
    unsigned short* ldsB = &As[(size_t)(32 + wave * 8) * 64];

    const bf16_t* Bp = Bt + (size_t)(n0 + l16) * KT + quad * 8;

    for (int c = 0; c < NC; ++c) {
        const bf16_t* Ah = (c < CPH) ? A1 : A2;
        int kk = ((c < CPH) ? c : (c - CPH)) * 64;
        gl_lds16(Ah + (size_t)(row0 + rA) * KH + kk + kswA, ldsA);
        gl_lds16(Ah + (size_t)(row0 + 32 + rA) * KH + kk + kswA, ldsB);
        __syncthreads();
        int bk = c * 64;
#pragma unroll
        for (int sub = 0; sub < 2; ++sub) {
            bf16x8 af[4], bfr[4];
#pragma unroll
            for (int mi = 0; mi < 4; ++mi) {
                int r = mi * 16 + l16;
                int qb = sub * 4 + quad;
                af[mi] = *(const bf16x8*)&As[r * 64 + ((qb ^ (r & 7)) << 3)];
            }
#pragma unroll
            for (int ni = 0; ni < 4; ++ni)
                bfr[ni] = *(const bf16x8*)(Bp + (size_t)(ni * 16) * KT + bk + sub * 32);
#pragma unroll
            for (int mi = 0; mi < 4; ++mi)
#pragma unroll
                for (int ni = 0; ni < 4; ++ni)
                    acc[mi][ni] = __builtin_amdgcn_mfma_f32_16x16x32_bf16(
                        af[mi], bfr[ni], acc[mi][ni], 0, 0, 0);
        }
        __syncthreads();
    }

    float bv[4];
#pragma unroll
    for (int ni = 0; ni < 4; ++ni) bv[ni] = bias[n0 + ni * 16 + l16];
    float mloc = 0.f;
#pragma unroll
    for (int mi = 0; mi < 4; ++mi) {
#pragma unroll
        for (int r = 0; r < 4; ++r) {
            int row = row0 + mi * 16 + quad * 4 + r;
            if (row < M) {
#pragma unroll
                for (int ni = 0; ni < 4; ++ni) {
                    int col = n0 + ni * 16 + l16;
                    float hv = fmaxf(acc[mi][ni][r] + bv[ni], 0.f);
                    mloc = fmaxf(mloc, hv);  // valid rows only
                    H[(size_t)row * 256 + col] = f2bf(hv);
                }
            }
        }
    }
    if (pmax) {
#pragma unroll
        for (int off = 32; off > 0; off >>= 1) mloc = fmaxf(mloc, __shfl_xor(mloc, off));
        if (lane == 0) wmax[wave] = mloc;
        __syncthreads();
        if (t == 0)
            pmax[blockIdx.x] = fmaxf(fmaxf(wmax[0], wmax[1]), fmaxf(wmax[2], wmax[3]));
    }
}

// ---------------- segmented mean pool (R9-proven: 64 rows/block, 4-row unroll) ----------------
__global__ __launch_bounds__(256) void pool_kernel(const unsigned short* __restrict__ h2,
                                                   const int* __restrict__ batch,
                                                   float* __restrict__ g, float* __restrict__ cnt,
                                                   int n) {
    int col = threadIdx.x;
    int row0 = blockIdx.x * 64;
    int rend = min(row0 + 64, n);
    float acc = 0.f;
    int cur = -1, seglen = 0;
    int r = row0;
    for (; r + 3 < rend; r += 4) {
        int b0 = batch[r], b1 = batch[r + 1], b2 = batch[r + 2], b3 = batch[r + 3];
        unsigned short v0 = h2[(size_t)r * 256 + col];
        unsigned short v1 = h2[(size_t)(r + 1) * 256 + col];
        unsigned short v2 = h2[(size_t)(r + 2) * 256 + col];
        unsigned short v3 = h2[(size_t)(r + 3) * 256 + col];
        int bs[4] = {b0, b1, b2, b3};
        unsigned short vs[4] = {v0, v1, v2, v3};
#pragma unroll
        for (int j = 0; j < 4; ++j) {
            if (bs[j] != cur) {
                if (cur >= 0) {
                    atomicAdd(&g[cur * 256 + col], acc);
                    if (col == 0) atomicAdd(&cnt[cur], (float)seglen);
                }
                acc = 0.f; cur = bs[j]; seglen = 0;
            }
            union { unsigned i; float f; } u;
            u.i = ((unsigned)vs[j]) << 16;
            acc += u.f;
            seglen++;
        }
    }
    for (; r < rend; ++r) {
        int b = batch[r];
        if (b != cur) {
            if (cur >= 0) {
                atomicAdd(&g[cur * 256 + col], acc);
                if (col == 0) atomicAdd(&cnt[cur], (float)seglen);
            }
            acc = 0.f; cur = b; seglen = 0;
        }
        union { unsigned i; float f; } u;
        u.i = ((unsigned)h2[(size_t)r * 256 + col]) << 16;
        acc += u.f;
        seglen++;
    }
    if (cur >= 0) {
        atomicAdd(&g[cur * 256 + col], acc);
        if (col == 0) atomicAdd(&cnt[cur], (float)seglen);
    }
}

// ---------------- classifier ----------------
__global__ void final_kernel(const float* __restrict__ g, const float* __restrict__ cnt,
                             const float* __restrict__ fcW, const float* __restrict__ fcb,
                             float* __restrict__ out) {
    int t = threadIdx.x;
    for (int o = t; o < NGRAPH * NCLS; o += 256) {
        int gi = o >> 4, c = o & 15;
        float inv = 1.f / fmaxf(cnt[gi], 1.f);
        float dot = 0.f;
        for (int k = 0; k < 256; ++k) dot += g[gi * 256 + k] * fcW[k * 16 + c];
        out[o] = dot * inv + fcb[c];
    }
}

extern "C" void kernel_launch(void* const* d_in, const int* in_sizes, int n_in, void* d_out,
                              int out_size, void* d_ws, size_t ws_size, hipStream_t stream) {
    const float* x   = (const float*)d_in[0];
    const int* edge  = (const int*)d_in[1];
    const int* batch = (const int*)d_in[2];
    const float* W1l = (const float*)d_in[3];
    const float* b1  = (const float*)d_in[4];
    const float* W1r = (const float*)d_in[5];
    const float* W2l = (const float*)d_in[6];
    const float* b2  = (const float*)d_in[7];
    const float* W2r = (const float*)d_in[8];
    const float* fcW = (const float*)d_in[9];
    const float* fcb = (const float*)d_in[10];
    float* out = (float*)d_out;

    const int n = in_sizes[0] / INDIM;   // 100000
    const int E = in_sizes[1] / 2;       // 1600000
    const int* src = edge;
    const int* dst = edge + E;
    const int nbuck = (n + 255) >> 8;    // 391

    char* ws = (char*)d_ws;
    size_t off = 0;
    auto alloc = [&](size_t bytes) {
        size_t p = off;
        off = (off + bytes + 511) & ~(size_t)511;
        return p;
    };
    size_t offs_o    = alloc((size_t)n * 4);
    size_t deg_o     = alloc((size_t)n * 4);          // zeroed
    size_t cnt_o     = alloc(64 * 4);                 // zeroed
    size_t g_o       = alloc(64 * 256 * 4);           // zeroed
    size_t gmax_o    = alloc(8);                      // gmaxx, gmaxh (written by reducemax)
    size_t zero_end  = off;
    size_t pmax_o    = alloc(12544 * 4);              // per-block max partials
    size_t bsum_o    = alloc(1024 * 4);
    size_t gcur_o    = alloc(512 * 4);
    size_t srclist_o = alloc((size_t)E * 4);
    size_t bt1_o     = alloc(256 * 256 * 2);
    size_t bt2_o     = alloc(256 * 512 * 2);
    size_t xbm2_o    = alloc((size_t)n * 256 * 2);    // xb16 (lower half) + xq8 (upper half) -> mean2
    size_t mean1_o   = alloc((size_t)n * 128 * 2);
    size_t h1_o      = alloc((size_t)n * 256 * 2);
    size_t h2_o      = alloc((size_t)n * 256 * 2);    // tmp (CSR build) / hq8 (upper half) -> h2b

    int*   offs    = (int*)(ws + offs_o);
    int*   deg     = (int*)(ws + deg_o);
    float* cnt     = (float*)(ws + cnt_o);
    float* g       = (float*)(ws + g_o);
    float* gmaxx   = (float*)(ws + gmax_o);
    float* gmaxh   = (float*)(ws + gmax_o + 4);
    float* pmax    = (float*)(ws + pmax_o);
    int*   bsum    = (int*)(ws + bsum_o);
    int*   gcur    = (int*)(ws + gcur_o);
    int*   srclist = (int*)(ws + srclist_o);
    unsigned short* Bt1   = (unsigned short*)(ws + bt1_o);
    unsigned short* Bt2   = (unsigned short*)(ws + bt2_o);
    unsigned short* xb16  = (unsigned short*)(ws + xbm2_o);                      // dead after gemm1
    unsigned char*  xq8   = (unsigned char*)(ws + xbm2_o + (size_t)n * 256);     // dead after agg1
    unsigned short* mean2 = (unsigned short*)(ws + xbm2_o);                      // written by agg2
    unsigned short* mean1 = (unsigned short*)(ws + mean1_o);
    unsigned short* h1b   = (unsigned short*)(ws + h1_o);
    unsigned*       tmp   = (unsigned*)(ws + h2_o);                              // dead after binB
    unsigned char*  hq8   = (unsigned char*)(ws + h2_o + (size_t)n * 256);       // dead after agg2
    unsigned short* h2b   = (unsigned short*)(ws + h2_o);                        // written by gemm2

    hipMemsetAsync(ws + deg_o, 0, zero_end - deg_o, stream);

    int eb = (E + 255) / 256;
    int nb = (n + 255) / 256;  // 391
    hist_kernel<<<eb, 256, 0, stream>>>(dst, deg, E);
    scan1_kernel<<<nb, 256, 0, stream>>>(deg, bsum, n);
    scan2_kernel<<<1, 1024, 0, stream>>>(bsum, nb);
    scan3_kernel<<<nb, 256, 0, stream>>>(deg, bsum, offs, gcur, n);
    binA_kernel<<<(E + CHUNK - 1) / CHUNK, 256, 0, stream>>>(src, dst, gcur, tmp, E, nbuck);
    binB_kernel<<<nbuck, 256, 0, stream>>>(tmp, offs, srclist, E, n);

    int castb = n * INDIM / 4 / 256;  // 12500
    prep_kernel<<<castb + 256 + 512, 256, 0, stream>>>(x, xb16, W1l, W1r, Bt1, W2l, W2r, Bt2,
                                                       pmax, castb);
    reducemax_kernel<<<1, 256, 0, stream>>>(pmax, castb, gmaxx);
    int xq4 = n * INDIM / 4;   // 3.2M
    quantx_kernel<<<(xq4 + 255) / 256, 256, 0, stream>>>(x, gmaxx, (unsigned*)xq8, xq4);

    int aggb = (n * 64 + 255) / 256;
    int gemmb = (n + 63) / 64;  // 1563

    agg1_kernel<<<aggb, 256, 0, stream>>>(xq8, srclist, offs, deg, gmaxx, mean1, n);
    gemm_kernel<128><<<gemmb, 256, 0, stream>>>(
        (const bf16_t*)mean1, (const bf16_t*)xb16, (const bf16_t*)Bt1, b1, h1b, pmax, n);
    reducemax_kernel<<<1, 256, 0, stream>>>(pmax, gemmb, gmaxh);
    int hq4 = n * HID / 4;     // 6.4M
    quanth_kernel<<<(hq4 + 255) / 256, 256, 0, stream>>>(h1b, gmaxh, (unsigned*)hq8, hq4);
    agg2_kernel<<<aggb, 256, 0, stream>>>(hq8, srclist, offs, deg, gmaxh, mean2, n);
    gemm_kernel<256><<<gemmb, 256, 0, stream>>>(
        (const bf16_t*)mean2, (const bf16_t*)h1b, (const bf16_t*)Bt2, b2, h2b,
        (float*)nullptr, n);

    pool_kernel<<<(n + 63) / 64, 256, 0, stream>>>(h2b, batch, g, cnt, n);
    final_kernel<<<1, 256, 0, stream>>>(g, cnt, fcW, fcb, out);
}

// Round 12
// 536.386 us; speedup vs baseline: 2.1484x; 1.0342x over previous
//
#include <hip/hip_runtime.h>

#define INDIM 128
#define HID 256
#define NCLS 16
#define NGRAPH 64
#define CHUNK 8192

typedef __bf16 bf16_t;
typedef bf16_t bf16x8 __attribute__((ext_vector_type(8)));
typedef float f32x4 __attribute__((ext_vector_type(4)));

__device__ __forceinline__ float bfu_lo(unsigned v) {
    union { unsigned i; float f; } u; u.i = v << 16; return u.f;
}
__device__ __forceinline__ float bfu_hi(unsigned v) {
    union { unsigned i; float f; } u; u.i = v & 0xffff0000u; return u.f;
}
__device__ __forceinline__ unsigned short f2bf(float f) {  // RNE
    union { float f; unsigned i; } u; u.f = f;
    unsigned b = u.i;
    return (unsigned short)((b + 0x7fffu + ((b >> 16) & 1u)) >> 16);
}
__device__ __forceinline__ unsigned packbf(float lo, float hi) {
    return (unsigned)f2bf(lo) | ((unsigned)f2bf(hi) << 16);
}

// async 16B global->LDS
typedef __attribute__((address_space(1))) const unsigned gu32_t;
typedef __attribute__((address_space(3))) unsigned lu32_t;
__device__ __forceinline__ void gl_lds16(const void* g, void* l) {
    __builtin_amdgcn_global_load_lds((gu32_t*)g, (lu32_t*)l, 16, 0, 0);
}

// SWAR: biased uint8 bytes accumulate as packed u16 pairs (exact; deg<256 => no overflow)
#define IACC(aE, aO, v)                              \
    do {                                             \
        aE[0] += ((v).x & 0x00FF00FFu);              \
        aO[0] += (((v).x >> 8) & 0x00FF00FFu);       \
        aE[1] += ((v).y & 0x00FF00FFu);              \
        aO[1] += (((v).y >> 8) & 0x00FF00FFu);       \
        aE[2] += ((v).z & 0x00FF00FFu);              \
        aO[2] += (((v).z >> 8) & 0x00FF00FFu);       \
        aE[3] += ((v).w & 0x00FF00FFu);              \
        aO[3] += (((v).w >> 8) & 0x00FF00FFu);       \
    } while (0)

// ---------------- CSR build ----------------
__global__ void hist_kernel(const int* __restrict__ dst, int* __restrict__ deg, int E) {
    int e = blockIdx.x * blockDim.x + threadIdx.x;
    if (e < E) atomicAdd(&deg[dst[e]], 1);
}

__global__ void scan1_kernel(const int* __restrict__ deg, int* __restrict__ bsum, int n) {
    __shared__ int s[256];
    int t = threadIdx.x;
    int i = blockIdx.x * 256 + t;
    s[t] = (i < n) ? deg[i] : 0;
    __syncthreads();
    for (int off = 128; off > 0; off >>= 1) {
        if (t < off) s[t] += s[t + off];
        __syncthreads();
    }
    if (t == 0) bsum[blockIdx.x] = s[0];
}

__global__ void scan2_kernel(int* bsum, int nb) {
    __shared__ int s[1024];
    int t = threadIdx.x;
    int v = (t < nb) ? bsum[t] : 0;
    s[t] = v;
    __syncthreads();
    for (int off = 1; off < 1024; off <<= 1) {
        int u = (t >= off) ? s[t - off] : 0;
        __syncthreads();
        s[t] += u;
        __syncthreads();
    }
    if (t < nb) bsum[t] = s[t] - v;  // exclusive
}

__global__ void scan3_kernel(const int* __restrict__ deg, const int* __restrict__ bsum,
                             int* __restrict__ offs, int* __restrict__ gcur, int n) {
    __shared__ int s[256];
    int t = threadIdx.x;
    int i = blockIdx.x * 256 + t;
    int v = (i < n) ? deg[i] : 0;
    s[t] = v;
    __syncthreads();
    for (int off = 1; off < 256; off <<= 1) {
        int u = (t >= off) ? s[t - off] : 0;
        __syncthreads();
        s[t] += u;
        __syncthreads();
    }
    if (i < n) offs[i] = s[t] - v + bsum[blockIdx.x];
    if (t == 0) gcur[blockIdx.x] = bsum[blockIdx.x];
}

// ---------------- two-phase locality-aware edge sort ----------------
__global__ __launch_bounds__(256) void binA_kernel(const int* __restrict__ src,
                                                   const int* __restrict__ dst,
                                                   int* __restrict__ gcur,
                                                   unsigned* __restrict__ tmp,
                                                   int E, int nbuck) {
    __shared__ int hist[512];
    __shared__ int base[512];
    int t = threadIdx.x;
    int e0 = blockIdx.x * CHUNK;
    int e1 = min(e0 + CHUNK, E);
    for (int i = t; i < nbuck; i += 256) hist[i] = 0;
    __syncthreads();
    for (int e = e0 + t; e < e1; e += 256) atomicAdd(&hist[dst[e] >> 8], 1);
    __syncthreads();
    for (int i = t; i < nbuck; i += 256) {
        int c = hist[i];
        base[i] = (c > 0) ? atomicAdd(&gcur[i], c) : 0;
    }
    __syncthreads();
    for (int e = e0 + t; e < e1; e += 256) {
        int d = dst[e];
        int p = atomicAdd(&base[d >> 8], 1);
        tmp[p] = ((unsigned)(d & 255) << 17) | (unsigned)src[e];  // src < 2^17
    }
}

__global__ __launch_bounds__(256) void binB_kernel(const unsigned* __restrict__ tmp,
                                                   const int* __restrict__ offs,
                                                   int* __restrict__ srclist, int E, int n) {
    __shared__ int cur[256];
    int b = blockIdx.x;
    int node0 = b << 8;
    int nnodes = min(256, n - node0);
    int t = threadIdx.x;
    if (t < nnodes) cur[t] = offs[node0 + t];
    __syncthreads();
    int ebeg = offs[node0];
    int eend = (node0 + 256 < n) ? offs[node0 + 256] : E;
    for (int e = ebeg + t; e < eend; e += 256) {
        unsigned v = tmp[e];
        int p = atomicAdd(&cur[v >> 17], 1);
        srclist[p] = (int)(v & 0x1FFFFu);
    }
}

// ---------------- merged prep (per-block max via plain store; R11-proven) ----------------
__global__ void prep_kernel(const float* __restrict__ x, unsigned short* __restrict__ xb,
                            const float* __restrict__ W1l, const float* __restrict__ W1r,
                            unsigned short* __restrict__ Bt1,
                            const float* __restrict__ W2l, const float* __restrict__ W2r,
                            unsigned short* __restrict__ Bt2, float* __restrict__ pmaxx,
                            int castb) {
    __shared__ float wmax[4];
    int b = blockIdx.x, t = threadIdx.x;
    if (b < castb) {
        int i4 = (b * 256 + t) * 4;
        float4 v = *(const float4*)(x + i4);
        *(ushort4*)(xb + i4) = make_ushort4(f2bf(v.x), f2bf(v.y), f2bf(v.z), f2bf(v.w));
        float m = fmaxf(fmaxf(fabsf(v.x), fabsf(v.y)), fmaxf(fabsf(v.z), fabsf(v.w)));
#pragma unroll
        for (int off = 32; off > 0; off >>= 1) m = fmaxf(m, __shfl_xor(m, off));
        if ((t & 63) == 0) wmax[t >> 6] = m;
        __syncthreads();
        if (t == 0)
            pmaxx[b] = fmaxf(fmaxf(wmax[0], wmax[1]), fmaxf(wmax[2], wmax[3]));
    } else if (b < castb + 256) {
        int idx = (b - castb) * 256 + t;
        int nn = idx >> 8, k = idx & 255;
        float v = (k < 128) ? W1l[(size_t)k * 256 + nn] : W1r[(size_t)(k - 128) * 256 + nn];
        Bt1[(size_t)nn * 256 + k] = f2bf(v);
    } else {
        int idx = (b - castb - 256) * 256 + t;
        int nn = idx >> 9, k = idx & 511;
        float v = (k < 256) ? W2l[(size_t)k * 256 + nn] : W2r[(size_t)(k - 256) * 256 + nn];
        Bt2[(size_t)nn * 512 + k] = f2bf(v);
    }
}

__global__ void reducemax_kernel(const float* __restrict__ pmax, int cnt,
                                 float* __restrict__ gmax) {
    __shared__ float wmax[4];
    int t = threadIdx.x;
    float m = 0.f;
    for (int i = t; i < cnt; i += 256) m = fmaxf(m, pmax[i]);
#pragma unroll
    for (int off = 32; off > 0; off >>= 1) m = fmaxf(m, __shfl_xor(m, off));
    if ((t & 63) == 0) wmax[t >> 6] = m;
    __syncthreads();
    if (t == 0) gmax[0] = fmaxf(fmaxf(wmax[0], wmax[1]), fmaxf(wmax[2], wmax[3]));
}

// graph sizes: per-block LDS histogram of sorted batch -> few atomics
__global__ void cnt_kernel(const int* __restrict__ batch, float* __restrict__ cnt, int n) {
    __shared__ int h[64];
    int t = threadIdx.x;
    if (t < 64) h[t] = 0;
    __syncthreads();
    int i = blockIdx.x * 256 + t;
    if (i < n) atomicAdd(&h[batch[i]], 1);
    __syncthreads();
    if (t < 64 && h[t] > 0) atomicAdd(&cnt[t], (float)h[t]);
}

// ---------------- int8 quantization (biased uint8, one global scale) ----------------
__global__ void quantx_kernel(const float* __restrict__ x, const float* __restrict__ gmaxp,
                              unsigned* __restrict__ xq, int total4) {
    int idx = blockIdx.x * blockDim.x + threadIdx.x;
    if (idx >= total4) return;
    float inv = 127.f / fmaxf(*gmaxp, 1e-20f);
    float4 v = *(const float4*)(x + idx * 4);
    int b0 = (int)fminf(fmaxf(rintf(v.x * inv), -127.f), 127.f) + 128;
    int b1 = (int)fminf(fmaxf(rintf(v.y * inv), -127.f), 127.f) + 128;
    int b2 = (int)fminf(fmaxf(rintf(v.z * inv), -127.f), 127.f) + 128;
    int b3 = (int)fminf(fmaxf(rintf(v.w * inv), -127.f), 127.f) + 128;
    xq[idx] = (unsigned)b0 | ((unsigned)b1 << 8) | ((unsigned)b2 << 16) | ((unsigned)b3 << 24);
}

__global__ void quanth_kernel(const unsigned short* __restrict__ h1, const float* __restrict__ gmaxp,
                              unsigned* __restrict__ hq, int total4) {
    int idx = blockIdx.x * blockDim.x + threadIdx.x;
    if (idx >= total4) return;
    float inv = 127.f / fmaxf(*gmaxp, 1e-20f);
    uint2 v = *(const uint2*)(h1 + idx * 4);
    int b0 = (int)fminf(rintf(bfu_lo(v.x) * inv), 127.f) + 128;
    int b1 = (int)fminf(rintf(bfu_hi(v.x) * inv), 127.f) + 128;
    int b2 = (int)fminf(rintf(bfu_lo(v.y) * inv), 127.f) + 128;
    int b3 = (int)fminf(rintf(bfu_hi(v.y) * inv), 127.f) + 128;
    hq[idx] = (unsigned)b0 | ((unsigned)b1 << 8) | ((unsigned)b2 << 16) | ((unsigned)b3 << 24);
}

// ---------------- int8 mean aggregation (R11-proven) ----------------
__global__ void agg1_kernel(const unsigned char* __restrict__ xq, const int* __restrict__ srclist,
                            const int* __restrict__ offs, const int* __restrict__ deg,
                            const float* __restrict__ gmaxp,
                            unsigned short* __restrict__ mean, int n) {
    int gid = blockIdx.x * blockDim.x + threadIdx.x;
    int node = gid >> 6, lane = gid & 63;
    if (node >= n) return;
    int g = lane >> 3, sub = lane & 7;
    int st = __builtin_amdgcn_readfirstlane(offs[node]);
    int d = __builtin_amdgcn_readfirstlane(deg[node]);
    int end = st + d;
    unsigned aE[4] = {0, 0, 0, 0}, aO[4] = {0, 0, 0, 0};
    unsigned bE[4] = {0, 0, 0, 0}, bO[4] = {0, 0, 0, 0};
    const unsigned char* rb = xq + sub * 16;
    int e = st;
    for (; e + 15 < end; e += 16) {
        int s0 = srclist[e + g];
        int s1 = srclist[e + 8 + g];
        uint4 v0 = *(const uint4*)(rb + (size_t)s0 * 128);
        uint4 v1 = *(const uint4*)(rb + (size_t)s1 * 128);
        IACC(aE, aO, v0);
        IACC(bE, bO, v1);
    }
    for (; e + 7 < end; e += 8) {
        int s0 = srclist[e + g];
        uint4 v0 = *(const uint4*)(rb + (size_t)s0 * 128);
        IACC(aE, aO, v0);
    }
    int rem = end - e;
    if (rem > 0) {
        int s0 = srclist[e + ((g < rem) ? g : 0)];
        uint4 v0 = *(const uint4*)(rb + (size_t)s0 * 128);
        if (g < rem) IACC(aE, aO, v0);
    }
#pragma unroll
    for (int j = 0; j < 4; ++j) {
        unsigned se = aE[j] + bE[j], so = aO[j] + bO[j];
        se += (unsigned)__shfl_xor((int)se, 8);
        se += (unsigned)__shfl_xor((int)se, 16);
        se += (unsigned)__shfl_xor((int)se, 32);
        so += (unsigned)__shfl_xor((int)so, 8);
        so += (unsigned)__shfl_xor((int)so, 16);
        so += (unsigned)__shfl_xor((int)so, 32);
        aE[j] = se;
        aO[j] = so;
    }
    if (g == 0) {
        float sc = (*gmaxp) * (1.f / 127.f);
        float invd = 1.f / fmaxf((float)d, 1.f);
        unsigned o[8];
#pragma unroll
        for (int j = 0; j < 4; ++j) {
            float m0 = sc * (float)((int)(aE[j] & 0xFFFFu) - 128 * d) * invd;
            float m1 = sc * (float)((int)(aO[j] & 0xFFFFu) - 128 * d) * invd;
            float m2 = sc * (float)((int)(aE[j] >> 16) - 128 * d) * invd;
            float m3 = sc * (float)((int)(aO[j] >> 16) - 128 * d) * invd;
            o[j * 2] = packbf(m0, m1);
            o[j * 2 + 1] = packbf(m2, m3);
        }
        uint4* p = (uint4*)(mean + (size_t)node * 128 + sub * 16);
        p[0] = make_uint4(o[0], o[1], o[2], o[3]);
        p[1] = make_uint4(o[4], o[5], o[6], o[7]);
    }
}

__global__ void agg2_kernel(const unsigned char* __restrict__ hq, const int* __restrict__ srclist,
                            const int* __restrict__ offs, const int* __restrict__ deg,
                            const float* __restrict__ gmaxp,
                            unsigned short* __restrict__ mean, int n) {
    int gid = blockIdx.x * blockDim.x + threadIdx.x;
    int node = gid >> 6, lane = gid & 63;
    if (node >= n) return;
    int g = lane >> 4, sub = lane & 15;
    int st = __builtin_amdgcn_readfirstlane(offs[node]);
    int d = __builtin_amdgcn_readfirstlane(deg[node]);
    int end = st + d;
    unsigned aE[4] = {0, 0, 0, 0}, aO[4] = {0, 0, 0, 0};
    unsigned bE[4] = {0, 0, 0, 0}, bO[4] = {0, 0, 0, 0};
    const unsigned char* rb = hq + sub * 16;
    int e = st;
    for (; e + 7 < end; e += 8) {
        int s0 = srclist[e + g];
        int s1 = srclist[e + 4 + g];
        uint4 v0 = *(const uint4*)(rb + (size_t)s0 * 256);
        uint4 v1 = *(const uint4*)(rb + (size_t)s1 * 256);
        IACC(aE, aO, v0);
        IACC(bE, bO, v1);
    }
    for (; e + 3 < end; e += 4) {
        int s0 = srclist[e + g];
        uint4 v0 = *(const uint4*)(rb + (size_t)s0 * 256);
        IACC(aE, aO, v0);
    }
    int rem = end - e;
    if (rem > 0) {
        int s0 = srclist[e + ((g < rem) ? g : 0)];
        uint4 v0 = *(const uint4*)(rb + (size_t)s0 * 256);
        if (g < rem) IACC(aE, aO, v0);
    }
#pragma unroll
    for (int j = 0; j < 4; ++j) {
        unsigned se = aE[j] + bE[j], so = aO[j] + bO[j];
        se += (unsigned)__shfl_xor((int)se, 16);
        se += (unsigned)__shfl_xor((int)se, 32);
        so += (unsigned)__shfl_xor((int)so, 16);
        so += (unsigned)__shfl_xor((int)so, 32);
        aE[j] = se;
        aO[j] = so;
    }
    if (g == 0) {
        float sc = (*gmaxp) * (1.f / 127.f);
        float invd = 1.f / fmaxf((float)d, 1.f);
        unsigned o[8];
#pragma unroll
        for (int j = 0; j < 4; ++j) {
            float m0 = sc * (float)((int)(aE[j] & 0xFFFFu) - 128 * d) * invd;
            float m1 = sc * (float)((int)(aO[j] & 0xFFFFu) - 128 * d) * invd;
            float m2 = sc * (float)((int)(aE[j] >> 16) - 128 * d) * invd;
            float m3 = sc * (float)((int)(aO[j] >> 16) - 128 * d) * invd;
            o[j * 2] = packbf(m0, m1);
            o[j * 2 + 1] = packbf(m2, m3);
        }
        uint4* p = (uint4*)(mean + (size_t)node * 256 + sub * 16);
        p[0] = make_uint4(o[0], o[1], o[2], o[3]);
        p[1] = make_uint4(o[4], o[5], o[6], o[7]);
    }
}

// ======== MFMA GEMM layer-1 (R11-proven; stores H + per-block max) ========
template <int KH>
__global__ __launch_bounds__(256) void gemm_kernel(
        const bf16_t* __restrict__ A1, const bf16_t* __restrict__ A2,
        const bf16_t* __restrict__ Bt, const float* __restrict__ bias,
        unsigned short* __restrict__ H, float* __restrict__ pmax, int M) {
    constexpr int KT = 2 * KH;
    constexpr int NC = KT / 64;
    constexpr int CPH = KH / 64;
    __shared__ unsigned short As[64 * 64];  // 8 KB
    __shared__ float wmax[4];
    int t = threadIdx.x, wave = t >> 6, lane = t & 63;
    int quad = lane >> 4, l16 = lane & 15;
    int row0 = blockIdx.x * 64, n0 = wave * 64;

    f32x4 acc[4][4];
#pragma unroll
    for (int i = 0; i < 4; ++i)
#pragma unroll
        for (int j = 0; j < 4; ++j) acc[i][j] = (f32x4)(0.f);

    int rA = wave * 8 + (lane >> 3);
    int kb = lane & 7;
    int kswA = (kb ^ (rA & 7)) << 3;
    unsigned short* ldsA = &As[(size_t)(wave * 8) * 64];
    unsigned short* ldsB = &As[(size_t)(32 + wave * 8) * 64];

    const bf16_t* Bp = Bt + (size_t)(n0 + l16) * KT + quad * 8;

    for (int c = 0; c < NC; ++c) {
        const bf16_t* Ah = (c < CPH) ? A1 : A2;
        int kk = ((c < CPH) ? c : (c - CPH)) * 64;
        gl_lds16(Ah + (size_t)(row0 + rA) * KH + kk + kswA, ldsA);
        gl_lds16(Ah + (size_t)(row0 + 32 + rA) * KH + kk + kswA, ldsB);
        __syncthreads();
        int bk = c * 64;
#pragma unroll
        for (int sub = 0; sub < 2; ++sub) {
            bf16x8 af[4], bfr[4];
#pragma unroll
            for (int mi = 0; mi < 4; ++mi) {
                int r = mi * 16 + l16;
                int qb = sub * 4 + quad;
                af[mi] = *(const bf16x8*)&As[r * 64 + ((qb ^ (r & 7)) << 3)];
            }
#pragma unroll
            for (int ni = 0; ni < 4; ++ni)
                bfr[ni] = *(const bf16x8*)(Bp + (size_t)(ni * 16) * KT + bk + sub * 32);
#pragma unroll
            for (int mi = 0; mi < 4; ++mi)
#pragma unroll
                for (int ni = 0; ni < 4; ++ni)
                    acc[mi][ni] = __builtin_amdgcn_mfma_f32_16x16x32_bf16(
                        af[mi], bfr[ni], acc[mi][ni], 0, 0, 0);
        }
        __syncthreads();
    }

    float bv[4];
#pragma unroll
    for (int ni = 0; ni < 4; ++ni) bv[ni] = bias[n0 + ni * 16 + l16];
    float mloc = 0.f;
#pragma unroll
    for (int mi = 0; mi < 4; ++mi) {
#pragma unroll
        for (int r = 0; r < 4; ++r) {
            int row = row0 + mi * 16 + quad * 4 + r;
            if (row < M) {
#pragma unroll
                for (int ni = 0; ni < 4; ++ni) {
                    int col = n0 + ni * 16 + l16;
                    float hv = fmaxf(acc[mi][ni][r] + bv[ni], 0.f);
                    mloc = fmaxf(mloc, hv);
                    H[(size_t)row * 256 + col] = f2bf(hv);
                }
            }
        }
    }
    if (pmax) {
#pragma unroll
        for (int off = 32; off > 0; off >>= 1) mloc = fmaxf(mloc, __shfl_xor(mloc, off));
        if (lane == 0) wmax[wave] = mloc;
        __syncthreads();
        if (t == 0)
            pmax[blockIdx.x] = fmaxf(fmaxf(wmax[0], wmax[1]), fmaxf(wmax[2], wmax[3]));
    }
}

// ======== layer-2 GEMM with FUSED mean-pool epilogue: h2 never materialized ========
// Pool = row-sum per graph; batch sorted => a 64-row block spans 1 graph ~96% of the
// time (segments ~1562 rows). Reduce fp32 accs across quads (shfl 16/32), one
// atomicAdd per (col, segment) per block: ~400K atomics over 16K addresses.
__global__ __launch_bounds__(256) void gemm2p_kernel(
        const bf16_t* __restrict__ A1, const bf16_t* __restrict__ A2,
        const bf16_t* __restrict__ Bt, const float* __restrict__ bias,
        const int* __restrict__ batch, float* __restrict__ g, int M) {
    constexpr int KH = 256, KT = 512, NC = 8, CPH = 4;
    __shared__ unsigned short As[64 * 64];  // 8 KB
    __shared__ int sbatch[64];
    int t = threadIdx.x, wave = t >> 6, lane = t & 63;
    int quad = lane >> 4, l16 = lane & 15;
    int row0 = blockIdx.x * 64, n0 = wave * 64;

    if (t < 64) sbatch[t] = (row0 + t < M) ? batch[row0 + t] : -1;

    f32x4 acc[4][4];
#pragma unroll
    for (int i = 0; i < 4; ++i)
#pragma unroll
        for (int j = 0; j < 4; ++j) acc[i][j] = (f32x4)(0.f);

    int rA = wave * 8 + (lane >> 3);
    int kb = lane & 7;
    int kswA = (kb ^ (rA & 7)) << 3;
    unsigned short* ldsA = &As[(size_t)(wave * 8) * 64];
    unsigned short* ldsB = &As[(size_t)(32 + wave * 8) * 64];

    const bf16_t* Bp = Bt + (size_t)(n0 + l16) * KT + quad * 8;

    for (int c = 0; c < NC; ++c) {
        const bf16_t* Ah = (c < CPH) ? A1 : A2;
        int kk = ((c < CPH) ? c : (c - CPH)) * 64;
        gl_lds16(Ah + (size_t)(row0 + rA) * KH + kk + kswA, ldsA);
        gl_lds16(Ah + (size_t)(row0 + 32 + rA) * KH + kk + kswA, ldsB);
        __syncthreads();
        int bk = c * 64;
#pragma unroll
        for (int sub = 0; sub < 2; ++sub) {
            bf16x8 af[4], bfr[4];
#pragma unroll
            for (int mi = 0; mi < 4; ++mi) {
                int r = mi * 16 + l16;
                int qb = sub * 4 + quad;
                af[mi] = *(const bf16x8*)&As[r * 64 + ((qb ^ (r & 7)) << 3)];
            }
#pragma unroll
            for (int ni = 0; ni < 4; ++ni)
                bfr[ni] = *(const bf16x8*)(Bp + (size_t)(ni * 16) * KT + bk + sub * 32);
#pragma unroll
            for (int mi = 0; mi < 4; ++mi)
#pragma unroll
                for (int ni = 0; ni < 4; ++ni)
                    acc[mi][ni] = __builtin_amdgcn_mfma_f32_16x16x32_bf16(
                        af[mi], bfr[ni], acc[mi][ni], 0, 0, 0);
        }
        __syncthreads();
    }

    float bv[4];
#pragma unroll
    for (int ni = 0; ni < 4; ++ni) bv[ni] = bias[n0 + ni * 16 + l16];

    int rlast = min(63, M - 1 - row0);
    int b0 = sbatch[0], b1 = sbatch[rlast];
    for (int gb = b0; gb <= b1; ++gb) {
        float colsum[4] = {0.f, 0.f, 0.f, 0.f};
#pragma unroll
        for (int mi = 0; mi < 4; ++mi) {
#pragma unroll
            for (int r = 0; r < 4; ++r) {
                int rl = mi * 16 + quad * 4 + r;
                if (sbatch[rl] == gb) {
#pragma unroll
                    for (int ni = 0; ni < 4; ++ni)
                        colsum[ni] += fmaxf(acc[mi][ni][r] + bv[ni], 0.f);
                }
            }
        }
#pragma unroll
        for (int ni = 0; ni < 4; ++ni) {
            colsum[ni] += __shfl_xor(colsum[ni], 16);
            colsum[ni] += __shfl_xor(colsum[ni], 32);
        }
        if (lane < 16) {
#pragma unroll
            for (int ni = 0; ni < 4; ++ni)
                atomicAdd(&g[gb * 256 + n0 + ni * 16 + l16], colsum[ni]);
        }
    }
}

// ---------------- classifier ----------------
__global__ void final_kernel(const float* __restrict__ g, const float* __restrict__ cnt,
                             const float* __restrict__ fcW, const float* __restrict__ fcb,
                             float* __restrict__ out) {
    int t = threadIdx.x;
    for (int o = t; o < NGRAPH * NCLS; o += 256) {
        int gi = o >> 4, c = o & 15;
        float inv = 1.f / fmaxf(cnt[gi], 1.f);
        float dot = 0.f;
        for (int k = 0; k < 256; ++k) dot += g[gi * 256 + k] * fcW[k * 16 + c];
        out[o] = dot * inv + fcb[c];
    }
}

extern "C" void kernel_launch(void* const* d_in, const int* in_sizes, int n_in, void* d_out,
                              int out_size, void* d_ws, size_t ws_size, hipStream_t stream) {
    const float* x   = (const float*)d_in[0];
    const int* edge  = (const int*)d_in[1];
    const int* batch = (const int*)d_in[2];
    const float* W1l = (const float*)d_in[3];
    const float* b1  = (const float*)d_in[4];
    const float* W1r = (const float*)d_in[5];
    const float* W2l = (const float*)d_in[6];
    const float* b2  = (const float*)d_in[7];
    const float* W2r = (const float*)d_in[8];
    const float* fcW = (const float*)d_in[9];
    const float* fcb = (const float*)d_in[10];
    float* out = (float*)d_out;

    const int n = in_sizes[0] / INDIM;   // 100000
    const int E = in_sizes[1] / 2;       // 1600000
    const int* src = edge;
    const int* dst = edge + E;
    const int nbuck = (n + 255) >> 8;    // 391

    char* ws = (char*)d_ws;
    size_t off = 0;
    auto alloc = [&](size_t bytes) {
        size_t p = off;
        off = (off + bytes + 511) & ~(size_t)511;
        return p;
    };
    size_t offs_o    = alloc((size_t)n * 4);
    size_t deg_o     = alloc((size_t)n * 4);          // zeroed
    size_t cnt_o     = alloc(64 * 4);                 // zeroed
    size_t g_o       = alloc(64 * 256 * 4);           // zeroed
    size_t gmax_o    = alloc(8);                      // gmaxx, gmaxh
    size_t zero_end  = off;
    size_t pmax_o    = alloc(12544 * 4);
    size_t bsum_o    = alloc(1024 * 4);
    size_t gcur_o    = alloc(512 * 4);
    size_t srclist_o = alloc((size_t)E * 4);
    size_t bt1_o     = alloc(256 * 256 * 2);
    size_t bt2_o     = alloc(256 * 512 * 2);
    size_t xbm2_o    = alloc((size_t)n * 256 * 2);    // xb16 (lower) + xq8 (upper) -> mean2
    size_t mean1_o   = alloc((size_t)n * 128 * 2);
    size_t h1_o      = alloc((size_t)n * 256 * 2);
    size_t aux_o     = alloc((size_t)n * 256 * 2);    // tmp (CSR build) / hq8 (upper half)

    int*   offs    = (int*)(ws + offs_o);
    int*   deg     = (int*)(ws + deg_o);
    float* cnt     = (float*)(ws + cnt_o);
    float* g       = (float*)(ws + g_o);
    float* gmaxx   = (float*)(ws + gmax_o);
    float* gmaxh   = (float*)(ws + gmax_o + 4);
    float* pmax    = (float*)(ws + pmax_o);
    int*   bsum    = (int*)(ws + bsum_o);
    int*   gcur    = (int*)(ws + gcur_o);
    int*   srclist = (int*)(ws + srclist_o);
    unsigned short* Bt1   = (unsigned short*)(ws + bt1_o);
    unsigned short* Bt2   = (unsigned short*)(ws + bt2_o);
    unsigned short* xb16  = (unsigned short*)(ws + xbm2_o);                      // dead after gemm1
    unsigned char*  xq8   = (unsigned char*)(ws + xbm2_o + (size_t)n * 256);     // dead after agg1
    unsigned short* mean2 = (unsigned short*)(ws + xbm2_o);                      // written by agg2
    unsigned short* mean1 = (unsigned short*)(ws + mean1_o);
    unsigned short* h1b   = (unsigned short*)(ws + h1_o);
    unsigned*       tmp   = (unsigned*)(ws + aux_o);                             // dead after binB
    unsigned char*  hq8   = (unsigned char*)(ws + aux_o + (size_t)n * 256);      // dead after agg2

    hipMemsetAsync(ws + deg_o, 0, zero_end - deg_o, stream);

    int eb = (E + 255) / 256;
    int nb = (n + 255) / 256;  // 391
    hist_kernel<<<eb, 256, 0, stream>>>(dst, deg, E);
    scan1_kernel<<<nb, 256, 0, stream>>>(deg, bsum, n);
    scan2_kernel<<<1, 1024, 0, stream>>>(bsum, nb);
    scan3_kernel<<<nb, 256, 0, stream>>>(deg, bsum, offs, gcur, n);
    binA_kernel<<<(E + CHUNK - 1) / CHUNK, 256, 0, stream>>>(src, dst, gcur, tmp, E, nbuck);
    binB_kernel<<<nbuck, 256, 0, stream>>>(tmp, offs, srclist, E, n);

    int castb = n * INDIM / 4 / 256;  // 12500
    prep_kernel<<<castb + 256 + 512, 256, 0, stream>>>(x, xb16, W1l, W1r, Bt1, W2l, W2r, Bt2,
                                                       pmax, castb);
    reducemax_kernel<<<1, 256, 0, stream>>>(pmax, castb, gmaxx);
    cnt_kernel<<<nb, 256, 0, stream>>>(batch, cnt, n);
    int xq4 = n * INDIM / 4;
    quantx_kernel<<<(xq4 + 255) / 256, 256, 0, stream>>>(x, gmaxx, (unsigned*)xq8, xq4);

    int aggb = (n * 64 + 255) / 256;
    int gemmb = (n + 63) / 64;  // 1563

    agg1_kernel<<<aggb, 256, 0, stream>>>(xq8, srclist, offs, deg, gmaxx, mean1, n);
    gemm_kernel<128><<<gemmb, 256, 0, stream>>>(
        (const bf16_t*)mean1, (const bf16_t*)xb16, (const bf16_t*)Bt1, b1, h1b, pmax, n);
    reducemax_kernel<<<1, 256, 0, stream>>>(pmax, gemmb, gmaxh);
    int hq4 = n * HID / 4;
    quanth_kernel<<<(hq4 + 255) / 256, 256, 0, stream>>>(h1b, gmaxh, (unsigned*)hq8, hq4);
    agg2_kernel<<<aggb, 256, 0, stream>>>(hq8, srclist, offs, deg, gmaxh, mean2, n);
    gemm2p_kernel<<<gemmb, 256, 0, stream>>>(
        (const bf16_t*)mean2, (const bf16_t*)h1b, (const bf16_t*)Bt2, b2, batch, g, n);

    final_kernel<<<1, 256, 0, stream>>>(g, cnt, fcW, fcb, out);
}